// Round 13
// baseline (2323.795 us; speedup 1.0000x reference)
//
#include <hip/hip_runtime.h>
#include <math.h>

#define NI 100000
#define NF 2000
#define NE 800000
#define NEF 200000
#define DN 16
#define NL 11
#define NT (2 * NI + NF)   // concatenated node-direction count: P | S | F
#define NBI 782            // inst blocks: ceil(NI/128)
#define NBF 125            // fin blocks: NF/16
#define WTN (64 * 168)     // wcat tile elements per layer
#define LROW 168           // LDS X-tile row stride (bf16 elems): 160 + 8 pad

typedef short bf16x8 __attribute__((ext_vector_type(8)));
typedef float f32x4 __attribute__((ext_vector_type(4)));

__device__ __forceinline__ float elu1(float x) { return x > 0.f ? x : expm1f(x); }

__device__ __forceinline__ unsigned short f2bf(float f) {
    unsigned x = __float_as_uint(f);
    return (unsigned short)((x + 0x7fffu + ((x >> 16) & 1u)) >> 16);
}
__device__ __forceinline__ float bf2f(unsigned short u) {
    return __uint_as_float(((unsigned)u) << 16);
}

// ---------------- CSR build (concatenated P|S|F degree array) ----------------
__global__ __launch_bounds__(256) void k_count(const int* __restrict__ prev_src,
                                               const int* __restrict__ prev_dst,
                                               const int* __restrict__ tf_dst,
                                               int* cnt) {
    int i = blockIdx.x * blockDim.x + threadIdx.x;
    if (i < NE) {
        atomicAdd(&cnt[prev_dst[i]], 1);
        atomicAdd(&cnt[NI + prev_src[i]], 1);
    }
    if (i < NEF) atomicAdd(&cnt[2 * NI + tf_dst[i]], 1);
}

__global__ __launch_bounds__(256) void k_scan1(const int* __restrict__ cnt, int n,
                                               int* __restrict__ rp, int* __restrict__ bsum) {
    __shared__ int s[256];
    int t = threadIdx.x, b = blockIdx.x, i = b * 256 + t;
    int v = (i < n) ? cnt[i] : 0;
    s[t] = v; __syncthreads();
    for (int o = 1; o < 256; o <<= 1) {
        int x = (t >= o) ? s[t - o] : 0;
        __syncthreads();
        s[t] += x;
        __syncthreads();
    }
    if (i < n) rp[i + 1] = s[t];
    if (t == 255) bsum[b] = s[255];
}

__global__ __launch_bounds__(1024) void k_scan2(int* __restrict__ bsum, int nb) {
    __shared__ int s[1024];
    int t = threadIdx.x;
    int v = (t < nb) ? bsum[t] : 0;
    s[t] = v; __syncthreads();
    for (int o = 1; o < 1024; o <<= 1) {
        int x = (t >= o) ? s[t - o] : 0;
        __syncthreads();
        s[t] += x;
        __syncthreads();
    }
    if (t < nb) bsum[t] = s[t] - v;   // exclusive block offsets
}

__global__ __launch_bounds__(256) void k_scan3(int* __restrict__ rp, const int* __restrict__ bsum, int n) {
    int i = blockIdx.x * blockDim.x + threadIdx.x;
    if (i < n) rp[i + 1] += bsum[i >> 8];
    if (i == 0) rp[0] = 0;
}

// ---------------- precompute bf16 GEMM weight tiles for all layers ----------------
__global__ __launch_bounds__(256) void k_prep_w(const float* __restrict__ Wg_prev,
                                                const float* __restrict__ Wg_succ,
                                                unsigned short* __restrict__ wcat) {
    int idx = blockIdx.x * blockDim.x + threadIdx.x;
    if (idx >= NL * WTN) return;
    int l = idx / WTN;
    int r = idx - l * WTN;
    int n = r / 168, k = r - n * 168;
    float v = 0.f;
    if (k < 72)       v = 0.5f * Wg_prev[(size_t)l * 72 * 64 + k * 64 + n];
    else if (k < 144) v = 0.5f * Wg_succ[(size_t)l * 72 * 64 + (k - 72) * 64 + n];
    wcat[idx] = f2bf(v);
}

// ---------------- scatter: CSR cols + fused edge-embed (fp32) in CSR slot order ----
__global__ __launch_bounds__(256) void k_scatter(const int* __restrict__ prev_src,
                                                 const int* __restrict__ prev_dst,
                                                 const int* __restrict__ tf_src,
                                                 const int* __restrict__ tf_dst,
                                                 const float* __restrict__ xe,
                                                 const float* __restrict__ xef,
                                                 const int* __restrict__ rp,
                                                 int* fill,
                                                 int* colP, int* colS, int* colF,
                                                 float* __restrict__ ePbuf,
                                                 float* __restrict__ eSbuf,
                                                 float* __restrict__ eFbuf,
                                                 const float* __restrict__ Wep, const float* __restrict__ bep,
                                                 const float* __restrict__ Wes, const float* __restrict__ bes,
                                                 const float* __restrict__ Wef, const float* __restrict__ bef) {
    int i = blockIdx.x * blockDim.x + threadIdx.x;
    if (i < NE) {
        int s = prev_src[i], d = prev_dst[i];
        float4 x0 = ((const float4*)xe)[(size_t)i * 2];
        float4 x1 = ((const float4*)xe)[(size_t)i * 2 + 1];
        float x[8] = {x0.x, x0.y, x0.z, x0.w, x1.x, x1.y, x1.z, x1.w};
        float eP[8], eS[8];
#pragma unroll
        for (int j = 0; j < 8; j++) {
            float vp = bep[j], vs = bes[j];
#pragma unroll
            for (int k = 0; k < 8; k++) { vp += x[k] * Wep[k * 8 + j]; vs += x[k] * Wes[k * 8 + j]; }
            eP[j] = elu1(vp); eS[j] = elu1(vs);
        }
        int tP = rp[d] + atomicAdd(&fill[d], 1);
        colP[tP] = s;
        ((float4*)ePbuf)[(size_t)tP * 2]     = make_float4(eP[0], eP[1], eP[2], eP[3]);
        ((float4*)ePbuf)[(size_t)tP * 2 + 1] = make_float4(eP[4], eP[5], eP[6], eP[7]);
        int tS = rp[NI + s] - NE + atomicAdd(&fill[NI + s], 1);
        colS[tS] = d;
        ((float4*)eSbuf)[(size_t)tS * 2]     = make_float4(eS[0], eS[1], eS[2], eS[3]);
        ((float4*)eSbuf)[(size_t)tS * 2 + 1] = make_float4(eS[4], eS[5], eS[6], eS[7]);
    }
    if (i < NEF) {
        int s = tf_src[i], d = tf_dst[i];
        float4 x0 = ((const float4*)xef)[(size_t)i * 2];
        float4 x1 = ((const float4*)xef)[(size_t)i * 2 + 1];
        float x[8] = {x0.x, x0.y, x0.z, x0.w, x1.x, x1.y, x1.z, x1.w};
        float eF[8];
#pragma unroll
        for (int j = 0; j < 8; j++) {
            float v = bef[j];
#pragma unroll
            for (int k = 0; k < 8; k++) v += x[k] * Wef[k * 8 + j];
            eF[j] = elu1(v);
        }
        int tF = rp[2 * NI + d] - 2 * NE + atomicAdd(&fill[2 * NI + d], 1);
        colF[tF] = s;
        ((float4*)eFbuf)[(size_t)tF * 2]     = make_float4(eF[0], eF[1], eF[2], eF[3]);
        ((float4*)eFbuf)[(size_t)tF * 2 + 1] = make_float4(eF[4], eF[5], eF[6], eF[7]);
    }
}

// ---------------- edge-embed aggregation: sequential run-sum per node ----------------
__global__ __launch_bounds__(256) void k_eagg2(const int* __restrict__ rp,
                                               const float* __restrict__ ePbuf,
                                               const float* __restrict__ eSbuf,
                                               const float* __restrict__ eFbuf,
                                               float* __restrict__ aggEp,
                                               float* __restrict__ aggEs,
                                               float* __restrict__ aggEf) {
    int idx = blockIdx.x * blockDim.x + threadIdx.x;
    if (idx >= NT) return;
    const float* buf; float* out; int s, e;
    if (idx < NF) {
        int n = idx;
        s = rp[2 * NI + n] - 2 * NE; e = rp[2 * NI + n + 1] - 2 * NE;
        buf = eFbuf; out = aggEf + (size_t)n * 8;
    } else if (idx < NF + NI) {
        int n = idx - NF;
        s = rp[n]; e = rp[n + 1];
        buf = ePbuf; out = aggEp + (size_t)n * 8;
    } else {
        int n = idx - NF - NI;
        s = rp[NI + n] - NE; e = rp[NI + n + 1] - NE;
        buf = eSbuf; out = aggEs + (size_t)n * 8;
    }
    float a0 = 0.f, a1 = 0.f, a2 = 0.f, a3 = 0.f, a4 = 0.f, a5 = 0.f, a6 = 0.f, a7 = 0.f;
    for (int t = s; t < e; ++t) {
        float4 v0 = ((const float4*)buf)[(size_t)t * 2];
        float4 v1 = ((const float4*)buf)[(size_t)t * 2 + 1];
        a0 += v0.x; a1 += v0.y; a2 += v0.z; a3 += v0.w;
        a4 += v1.x; a5 += v1.y; a6 += v1.z; a7 += v1.w;
    }
    ((float4*)out)[0] = make_float4(a0, a1, a2, a3);
    ((float4*)out)[1] = make_float4(a4, a5, a6, a7);
}

// ---------------- prep Xme: layer-invariant me-columns (compact, bf16) ----------------
__global__ __launch_bounds__(256) void k_prep_x(const int* __restrict__ rpAll,
                                                const float* __restrict__ aggEp,
                                                const float* __restrict__ aggEs,
                                                unsigned short* __restrict__ Xme) {
    int i = blockIdx.x * blockDim.x + threadIdx.x;
    if (i >= NI) return;
    int cP = rpAll[i + 1] - rpAll[i];
    int cS = rpAll[NI + i + 1] - rpAll[NI + i];
    float invP = 1.f / (float)max(cP, 1);
    float invS = 1.f / (float)max(cS, 1);
    unsigned short* xr = Xme + (size_t)i * 16;
#pragma unroll
    for (int c = 0; c < 2; c++) {
        float4 ep = ((const float4*)(aggEp + (size_t)i * 8))[c];
        float4 es = ((const float4*)(aggEs + (size_t)i * 8))[c];
        ushort4 up; up.x = f2bf(ep.x * invP); up.y = f2bf(ep.y * invP);
                    up.z = f2bf(ep.z * invP); up.w = f2bf(ep.w * invP);
        ushort4 us; us.x = f2bf(es.x * invS); us.y = f2bf(es.y * invS);
                    us.z = f2bf(es.z * invS); us.w = f2bf(es.w * invS);
        ((ushort4*)xr)[c]     = up;   // meP -> Xme[0..7]
        ((ushort4*)xr)[2 + c] = us;   // meS -> Xme[8..15]
    }
}

// ---------------- node embedding (wave per node, lane = output feature) ----------------
__global__ __launch_bounds__(256) void k_node_embed(const float* __restrict__ xi,
                                                    const float* __restrict__ xf,
                                                    const float* __restrict__ Wit, const float* __restrict__ bit,
                                                    const float* __restrict__ Wft, const float* __restrict__ bft,
                                                    float* __restrict__ inst, unsigned short* __restrict__ inst_bf,
                                                    float* __restrict__ fin) {
    const int NPW = 16;
    int lane = threadIdx.x & 63;
    int wave = (blockIdx.x * blockDim.x + threadIdx.x) >> 6;
    int base = wave * NPW;
    float wi[DN], wf[DN];
#pragma unroll
    for (int k = 0; k < DN; k++) { wi[k] = Wit[k * 64 + lane]; wf[k] = Wft[k * 64 + lane]; }
    float bi = bit[lane], bf = bft[lane];
    for (int n = 0; n < NPW; n++) {
        int i = base + n;
        if (i < NI) {
            const float4* x4 = (const float4*)(xi + (size_t)i * DN);
            float4 xa = x4[0], xb = x4[1], xc = x4[2], xd = x4[3];
            float x[DN] = {xa.x, xa.y, xa.z, xa.w, xb.x, xb.y, xb.z, xb.w,
                           xc.x, xc.y, xc.z, xc.w, xd.x, xd.y, xd.z, xd.w};
            float acc = bi;
#pragma unroll
            for (int k = 0; k < DN; k++) acc += x[k] * wi[k];
            float v = elu1(acc);
            inst[(size_t)i * 64 + lane] = v;
            inst_bf[(size_t)i * 64 + lane] = f2bf(v);
        } else if (i < NI + NF) {
            int f = i - NI;
            const float4* x4 = (const float4*)(xf + (size_t)f * DN);
            float4 xa = x4[0], xb = x4[1], xc = x4[2], xd = x4[3];
            float x[DN] = {xa.x, xa.y, xa.z, xa.w, xb.x, xb.y, xb.z, xb.w,
                           xc.x, xc.y, xc.z, xc.w, xd.x, xd.y, xd.z, xd.w};
            float acc = bf;
#pragma unroll
            for (int k = 0; k < DN; k++) acc += x[k] * wf[k];
            fin[(size_t)f * 64 + lane] = elu1(acc);
        }
    }
}

// gather-mean chain (verbatim round-8/10 structure): 8 lanes per task, lane f8 owns
// features f8*8..+8; fp32 adds in strictly ascending CSR order. Returns a[8].
__device__ __forceinline__ void spmm_chain(const unsigned short* __restrict__ src,
                                           const int* __restrict__ col,
                                           int s, int e1, float* a) {
#pragma unroll
    for (int j = 0; j < 8; j++) a[j] = 0.f;
    int pos = s;
    for (; pos + 8 <= e1; pos += 8) {
        int c[8];
#pragma unroll
        for (int u = 0; u < 8; u++) c[u] = col[pos + u];
        bf16x8 v[8];
#pragma unroll
        for (int u = 0; u < 8; u++) v[u] = *(const bf16x8*)(src + (size_t)c[u] * 64);
#pragma unroll
        for (int u = 0; u < 8; u++) {
#pragma unroll
            for (int j = 0; j < 8; j++) a[j] += bf2f((unsigned short)v[u][j]);
        }
    }
    for (; pos + 4 <= e1; pos += 4) {
        int c0 = col[pos], c1 = col[pos + 1], c2 = col[pos + 2], c3 = col[pos + 3];
        bf16x8 v0 = *(const bf16x8*)(src + (size_t)c0 * 64);
        bf16x8 v1 = *(const bf16x8*)(src + (size_t)c1 * 64);
        bf16x8 v2 = *(const bf16x8*)(src + (size_t)c2 * 64);
        bf16x8 v3 = *(const bf16x8*)(src + (size_t)c3 * 64);
#pragma unroll
        for (int j = 0; j < 8; j++) a[j] += bf2f((unsigned short)v0[j]);
#pragma unroll
        for (int j = 0; j < 8; j++) a[j] += bf2f((unsigned short)v1[j]);
#pragma unroll
        for (int j = 0; j < 8; j++) a[j] += bf2f((unsigned short)v2[j]);
#pragma unroll
        for (int j = 0; j < 8; j++) a[j] += bf2f((unsigned short)v3[j]);
    }
    for (; pos < e1; ++pos) {
        int c = col[pos];
        bf16x8 v = *(const bf16x8*)(src + (size_t)c * 64);
#pragma unroll
        for (int j = 0; j < 8; j++) a[j] += bf2f((unsigned short)v[j]);
    }
}

// ---------------- fused per-layer kernel (double-buffered inst_bf) ----------------
// READS inst_bf_in (previous layer), WRITES inst_bf_out (next layer) — distinct
// buffers, so concurrent blocks' gathers never observe this layer's updates
// (fixes the round-12 race; values bit-identical to the unfused round-11 kernel).
// blocks [0, NBI): inst path. Phase 1: spmm P/S for 128 nodes into LDS X-tile.
// Phase 2: MFMA GEMM (A from LDS, B from global wcat_l) + residual/elu epilogue.
// blocks [NBI, NBI+NBF): fin path (block-local, reads inst_bf_in only).
__global__ __launch_bounds__(256) void k_layer(
    const unsigned short* __restrict__ inst_bf_in,
    const int* __restrict__ rp,
    const int* __restrict__ colP, const int* __restrict__ colS, const int* __restrict__ colF,
    const unsigned short* __restrict__ Xme,
    float* __restrict__ inst, unsigned short* __restrict__ inst_bf_out,
    const unsigned short* __restrict__ wcat_l,
    const float* __restrict__ bp, const float* __restrict__ bs,
    float* __restrict__ fin,
    const float* __restrict__ aggEf,
    const float* __restrict__ Wf, const float* __restrict__ bf) {
    __shared__ __align__(16) unsigned short sh[128 * LROW];   // 43008 B
    int t = threadIdx.x;
    int wave = t >> 6, lane = t & 63;
    int n3 = lane >> 3, f8 = lane & 7;

    if (blockIdx.x < NBI) {
        int rowbase = blockIdx.x * 128;
        // ---- stage me cols + zero pad ----
        {
            int row = t >> 1, sel = t & 1;
            int node = min(rowbase + row, NI - 1);
            const unsigned short* xm = Xme + (size_t)node * 16;
            unsigned short* xr = sh + row * LROW;
            ushort4 z4; z4.x = z4.y = z4.z = z4.w = 0;
            if (sel == 0) {
                *(ushort4*)(xr + 64) = *(const ushort4*)(xm);
                *(ushort4*)(xr + 68) = *(const ushort4*)(xm + 4);
                *(ushort4*)(xr + 144) = z4;
                *(ushort4*)(xr + 148) = z4;
            } else {
                *(ushort4*)(xr + 136) = *(const ushort4*)(xm + 8);
                *(ushort4*)(xr + 140) = *(const ushort4*)(xm + 12);
                *(ushort4*)(xr + 152) = z4;
                *(ushort4*)(xr + 156) = z4;
            }
        }
        // ---- phase 1: spmm P/S into LDS X-tile (verbatim chain) ----
        const unsigned short* src = inst_bf_in + f8 * 8;
        for (int rep = 0; rep < 8; rep++) {
            int tl = rep * 32 + wave * 8 + n3;       // 0..255
            int node_local = tl >> 1, dir = tl & 1;
            int node = rowbase + node_local;
            if (node < NI) {
                const int* col = dir ? colS : colP;
                int rb_ = dir ? NI : 0, eb = dir ? NE : 0, xoff = dir ? 72 : 0;
                int s = rp[rb_ + node] - eb, e1 = rp[rb_ + node + 1] - eb;
                float a[8];
                spmm_chain(src, col, s, e1, a);
                int cnt = e1 - s;
                float inv = cnt > 0 ? 1.f / (float)cnt : 0.f;
                ushort4 o0, o1;
                o0.x = f2bf(a[0] * inv); o0.y = f2bf(a[1] * inv);
                o0.z = f2bf(a[2] * inv); o0.w = f2bf(a[3] * inv);
                o1.x = f2bf(a[4] * inv); o1.y = f2bf(a[5] * inv);
                o1.z = f2bf(a[6] * inv); o1.w = f2bf(a[7] * inv);
                unsigned short* dst = sh + node_local * LROW + xoff + f8 * 8;
                *(ushort4*)dst = o0;
                *(ushort4*)(dst + 4) = o1;
            }
        }
        __syncthreads();

        // ---- phase 2: MFMA GEMM (A from LDS, B from global wcat_l) ----
        int lrow = lane & 15, lk = (lane >> 4) * 8;
        int wrow = wave * 32;                         // wave's first local row

        f32x4 acc[2][4];
#pragma unroll
        for (int rb = 0; rb < 2; rb++)
#pragma unroll
            for (int nb = 0; nb < 4; nb++) acc[rb][nb] = (f32x4){0.f, 0.f, 0.f, 0.f};

#pragma unroll
        for (int kc = 0; kc < 5; kc++) {
            int k0 = kc * 32 + lk;
            bf16x8 a[2], b[4];
#pragma unroll
            for (int rb = 0; rb < 2; rb++)
                a[rb] = *(const bf16x8*)(sh + (wrow + rb * 16 + lrow) * LROW + k0);
#pragma unroll
            for (int nb = 0; nb < 4; nb++)
                b[nb] = *(const bf16x8*)(wcat_l + (size_t)(nb * 16 + lrow) * 168 + k0);
#pragma unroll
            for (int rb = 0; rb < 2; rb++)
#pragma unroll
                for (int nb = 0; nb < 4; nb++)
                    acc[rb][nb] = __builtin_amdgcn_mfma_f32_16x16x32_bf16(a[rb], b[nb], acc[rb][nb], 0, 0, 0);
        }

        // epilogue: C[row = (lane>>4)*4+j, col = nb*16 + lrow]
#pragma unroll
        for (int rb = 0; rb < 2; rb++) {
#pragma unroll
            for (int j = 0; j < 4; j++) {
                int node = rowbase + wrow + rb * 16 + (lane >> 4) * 4 + j;
                bool v = node < NI;
                int nn = v ? node : NI - 1;
                float mP = (v && (rp[nn + 1] > rp[nn])) ? 0.5f : 0.f;
                float mS = (v && (rp[NI + nn + 1] > rp[NI + nn])) ? 0.5f : 0.f;
#pragma unroll
                for (int nb = 0; nb < 4; nb++) {
                    int col = nb * 16 + lrow;
                    float x = inst[(size_t)nn * 64 + col] + acc[rb][nb][j] + mP * bp[col] + mS * bs[col];
                    x = elu1(x);
                    if (v) {
                        inst[(size_t)nn * 64 + col] = x;
                        inst_bf_out[(size_t)nn * 64 + col] = f2bf(x);
                    }
                }
            }
        }
    } else {
        // ---------- fin path ----------
        int nbase = (blockIdx.x - NBI) * 16;
        float* aggH = (float*)sh;                    // [16][64] fp32
        if (wave < 2) {
            int nl = wave * 8 + n3;                  // 0..15
            int node = nbase + nl;
            const unsigned short* src = inst_bf_in + f8 * 8;
            int s = rp[2 * NI + node] - 2 * NE, e1 = rp[2 * NI + node + 1] - 2 * NE;
            float a[8];
            spmm_chain(src, colF, s, e1, a);
            int cnt = e1 - s;
            float inv = cnt > 0 ? 1.f / (float)cnt : 0.f;
            float* dst = aggH + nl * 64 + f8 * 8;
            *(float4*)dst = make_float4(a[0] * inv, a[1] * inv, a[2] * inv, a[3] * inv);
            *(float4*)(dst + 4) = make_float4(a[4] * inv, a[5] * inv, a[6] * inv, a[7] * inv);
        }
        __syncthreads();

        // phase 2: thread = (node, j-quad), verbatim fin chain
        int n4 = t >> 4;                             // node local 0..15
        int jq = t & 15;                             // j-quad
        int n = nbase + n4;
        const int* rpF = rp + 2 * NI;
        int cF = rpF[n + 1] - rpF[n];
        float mF = (cF > 0) ? 1.f : 0.f;
        float invF = 1.f / (float)max(cF, 1);

        float acc0 = bf[jq * 4 + 0], acc1 = bf[jq * 4 + 1];
        float acc2 = bf[jq * 4 + 2], acc3 = bf[jq * 4 + 3];
        const float* hrow = aggH + n4 * 64;
        for (int k = 0; k < 64; k++) {
            float h = hrow[k];
            float4 w = *(const float4*)(Wf + (size_t)k * 64 + jq * 4);
            acc0 += h * w.x; acc1 += h * w.y; acc2 += h * w.z; acc3 += h * w.w;
        }
        const float* erow = aggEf + (size_t)n * 8;
#pragma unroll
        for (int k = 0; k < 8; k++) {
            float h = erow[k] * invF;
            float4 w = *(const float4*)(Wf + (size_t)(64 + k) * 64 + jq * 4);
            acc0 += h * w.x; acc1 += h * w.y; acc2 += h * w.z; acc3 += h * w.w;
        }
        float4 fv = *(const float4*)(fin + (size_t)n * 64 + jq * 4);
        float4 o;
        o.x = elu1(fv.x + mF * acc0);
        o.y = elu1(fv.y + mF * acc1);
        o.z = elu1(fv.z + mF * acc2);
        o.w = elu1(fv.w + mF * acc3);
        *(float4*)(fin + (size_t)n * 64 + jq * 4) = o;
    }
}

// ---------------- readout head ----------------
__global__ __launch_bounds__(64, 1) void k_head(
    const float* __restrict__ fin,
    const float* __restrict__ Wr1, const float* __restrict__ br1,
    const float* __restrict__ Wr2, const float* __restrict__ br2,
    const float* __restrict__ Wr3, const float* __restrict__ br3,
    float* __restrict__ out) {
    __shared__ float hL[64 * 65];
    const int lane = threadIdx.x;
    const int base = blockIdx.x * 64;

    for (int idx = lane; idx < 1024; idx += 64) {
        int n = idx >> 4, k4 = idx & 15;
        float4 v = ((const float4*)fin)[(size_t)min(base + n, NF - 1) * 16 + k4];
        float* d = &hL[n * 65 + k4 * 4];
        d[0] = v.x; d[1] = v.y; d[2] = v.z; d[3] = v.w;
    }
    __syncthreads();

    float acc[64];
#pragma unroll
    for (int j = 0; j < 64; j++) acc[j] = br1[j];
#pragma unroll 4
    for (int k = 0; k < 64; k++) {
        float h = hL[lane * 65 + k];
#pragma unroll
        for (int j = 0; j < 64; j++) acc[j] += h * Wr1[k * 64 + j];
    }
#pragma unroll
    for (int j = 0; j < 64; j++) hL[lane * 65 + j] = elu1(acc[j]);

#pragma unroll
    for (int j = 0; j < 64; j++) acc[j] = br2[j];
#pragma unroll 4
    for (int k = 0; k < 64; k++) {
        float h = hL[lane * 65 + k];
#pragma unroll
        for (int j = 0; j < 64; j++) acc[j] += h * Wr2[k * 64 + j];
    }
    float r = br3[0];
#pragma unroll
    for (int j = 0; j < 64; j++) r += elu1(acc[j]) * Wr3[j];

    int i = base + lane;
    if (i < NF) out[i] = r;
}

extern "C" void kernel_launch(void* const* d_in, const int* in_sizes, int n_in,
                              void* d_out, int out_size, void* d_ws, size_t ws_size,
                              hipStream_t stream) {
    const float* xi  = (const float*)d_in[0];
    const float* xf  = (const float*)d_in[1];
    const float* xe  = (const float*)d_in[2];
    const float* xef = (const float*)d_in[3];
    const int* prev_src = (const int*)d_in[4];
    const int* prev_dst = (const int*)d_in[5];
    const int* tf_src = (const int*)d_in[6];
    const int* tf_dst = (const int*)d_in[7];
    const float* W_it = (const float*)d_in[8];  const float* b_it = (const float*)d_in[9];
    const float* W_ft = (const float*)d_in[10]; const float* b_ft = (const float*)d_in[11];
    const float* W_ep = (const float*)d_in[12]; const float* b_ep = (const float*)d_in[13];
    const float* W_es = (const float*)d_in[14]; const float* b_es = (const float*)d_in[15];
    const float* W_ef = (const float*)d_in[16]; const float* b_ef = (const float*)d_in[17];
    const float* Wg_prev = (const float*)d_in[18]; const float* bg_prev = (const float*)d_in[19];
    const float* Wg_succ = (const float*)d_in[20]; const float* bg_succ = (const float*)d_in[21];
    const float* Wg_tf   = (const float*)d_in[22]; const float* bg_tf   = (const float*)d_in[23];
    const float* Wr1 = (const float*)d_in[24]; const float* br1 = (const float*)d_in[25];
    const float* Wr2 = (const float*)d_in[26]; const float* br2 = (const float*)d_in[27];
    const float* Wr3 = (const float*)d_in[28]; const float* br3 = (const float*)d_in[29];

    char* ws = (char*)d_ws;
    size_t off = 0;
    auto alloc = [&](size_t bytes) -> char* {
        char* p = ws + off;
        off += (bytes + 255) & ~(size_t)255;
        return p;
    };
    float* inst  = (float*)alloc((size_t)NI * 64 * 4);
    unsigned short* inst_bfA = (unsigned short*)alloc((size_t)NI * 64 * 2);
    unsigned short* inst_bfB = (unsigned short*)alloc((size_t)NI * 64 * 2);
    float* ePbuf = (float*)alloc((size_t)NE * 8 * 4);
    unsigned short* Xme = (unsigned short*)alloc((size_t)NI * 16 * 2);
    float* fin   = (float*)alloc((size_t)NF * 64 * 4);
    float* aggEp = (float*)alloc((size_t)NI * 8 * 4);
    float* aggEs = (float*)alloc((size_t)NI * 8 * 4);
    float* aggEf = (float*)alloc((size_t)NF * 8 * 4);
    unsigned short* wcat = (unsigned short*)alloc((size_t)NL * WTN * 2);
    char* zero_begin = ws + off;
    int* cnt  = (int*)alloc((size_t)NT * 4);
    int* fill = (int*)alloc((size_t)NT * 4);
    char* zero_end = ws + off;
    int* rpAll = (int*)alloc((size_t)(NT + 1) * 4);
    int* colP = (int*)alloc((size_t)NE * 4);
    int* colS = (int*)alloc((size_t)NE * 4);
    int* colF = (int*)alloc((size_t)NEF * 4);
    int* bsum = (int*)alloc(1024 * 4);
    (void)ws_size; (void)in_sizes; (void)n_in; (void)out_size;

    // scatter-stage fp32 edge-embed buffers: ePbuf owns storage; the others alias
    // regions dead until after k_eagg2:
    //   eSbuf (NE*32B = 25.6MB)  -> inst (25.6MB, first written by k_node_embed)
    //   eFbuf (NEF*32B = 6.4MB)  -> inst_bfA+inst_bfB (25.6MB, first written after eagg2)
    float* eSbuf = inst;
    float* eFbuf = (float*)inst_bfA;

    hipMemsetAsync(zero_begin, 0, (size_t)(zero_end - zero_begin), stream);

    k_prep_w<<<(NL * WTN + 255) / 256, 256, 0, stream>>>(Wg_prev, Wg_succ, wcat);

    k_count<<<(NE + 255) / 256, 256, 0, stream>>>(prev_src, prev_dst, tf_dst, cnt);

    int nb = (NT + 255) / 256;
    k_scan1<<<nb, 256, 0, stream>>>(cnt, NT, rpAll, bsum);
    k_scan2<<<1, 1024, 0, stream>>>(bsum, nb);
    k_scan3<<<nb, 256, 0, stream>>>(rpAll, bsum, NT);

    k_scatter<<<(NE + 255) / 256, 256, 0, stream>>>(prev_src, prev_dst, tf_src, tf_dst,
                                                    xe, xef, rpAll, fill,
                                                    colP, colS, colF,
                                                    ePbuf, eSbuf, eFbuf,
                                                    W_ep, b_ep, W_es, b_es, W_ef, b_ef);

    k_eagg2<<<(NT + 255) / 256, 256, 0, stream>>>(rpAll, ePbuf, eSbuf, eFbuf,
                                                  aggEp, aggEs, aggEf);

    k_prep_x<<<(NI + 255) / 256, 256, 0, stream>>>(rpAll, aggEp, aggEs, Xme);

    {
        int waves = (NI + NF + 15) / 16;
        int blocks = (waves + 3) / 4;
        k_node_embed<<<blocks, 256, 0, stream>>>(xi, xf, W_it, b_it, W_ft, b_ft,
                                                 inst, inst_bfA, fin);
    }

    unsigned short* bufs[2] = {inst_bfA, inst_bfB};
    for (int l = 0; l < NL; l++) {
        k_layer<<<NBI + NBF, 256, 0, stream>>>(bufs[l & 1], rpAll,
                                               colP, colS, colF, Xme,
                                               inst, bufs[(l + 1) & 1],
                                               wcat + (size_t)l * WTN,
                                               bg_prev + (size_t)l * 64, bg_succ + (size_t)l * 64,
                                               fin, aggEf,
                                               Wg_tf + (size_t)l * 72 * 64, bg_tf + (size_t)l * 64);
    }

    k_head<<<(NF + 63) / 64, 64, 0, stream>>>(fin, Wr1, br1, Wr2, br2, Wr3, br3, (float*)d_out);
}

// Round 14
// 1085.090 us; speedup vs baseline: 2.1416x; 2.1416x over previous
//
#include <hip/hip_runtime.h>
#include <math.h>

#define NI 100000
#define NF 2000
#define NE 800000
#define NEF 200000
#define DN 16
#define NL 11
#define NT (2 * NI + NF)   // concatenated node-direction count: P | S | F
#define KX 160             // padded K stride of X (bf16): 64 P | 8 meP | 64 S | 8 meS | 16 zero
#define NBI 782            // inst GEMM blocks: ceil(NI/128)
#define NBF 125            // fin blocks: NF*16/256
#define WTN (64 * 168)     // wcat tile elements per layer

typedef short bf16x8 __attribute__((ext_vector_type(8)));
typedef float f32x4 __attribute__((ext_vector_type(4)));

__device__ __forceinline__ float elu1(float x) { return x > 0.f ? x : expm1f(x); }

__device__ __forceinline__ unsigned short f2bf(float f) {
    unsigned x = __float_as_uint(f);
    return (unsigned short)((x + 0x7fffu + ((x >> 16) & 1u)) >> 16);
}
__device__ __forceinline__ float bf2f(unsigned short u) {
    return __uint_as_float(((unsigned)u) << 16);
}

// ---------------- CSR build (concatenated P|S|F degree array) ----------------
__global__ __launch_bounds__(256) void k_count(const int* __restrict__ prev_src,
                                               const int* __restrict__ prev_dst,
                                               const int* __restrict__ tf_dst,
                                               int* cnt) {
    int i = blockIdx.x * blockDim.x + threadIdx.x;
    if (i < NE) {
        atomicAdd(&cnt[prev_dst[i]], 1);
        atomicAdd(&cnt[NI + prev_src[i]], 1);
    }
    if (i < NEF) atomicAdd(&cnt[2 * NI + tf_dst[i]], 1);
}

__global__ __launch_bounds__(256) void k_scan1(const int* __restrict__ cnt, int n,
                                               int* __restrict__ rp, int* __restrict__ bsum) {
    __shared__ int s[256];
    int t = threadIdx.x, b = blockIdx.x, i = b * 256 + t;
    int v = (i < n) ? cnt[i] : 0;
    s[t] = v; __syncthreads();
    for (int o = 1; o < 256; o <<= 1) {
        int x = (t >= o) ? s[t - o] : 0;
        __syncthreads();
        s[t] += x;
        __syncthreads();
    }
    if (i < n) rp[i + 1] = s[t];
    if (t == 255) bsum[b] = s[255];
}

__global__ __launch_bounds__(1024) void k_scan2(int* __restrict__ bsum, int nb) {
    __shared__ int s[1024];
    int t = threadIdx.x;
    int v = (t < nb) ? bsum[t] : 0;
    s[t] = v; __syncthreads();
    for (int o = 1; o < 1024; o <<= 1) {
        int x = (t >= o) ? s[t - o] : 0;
        __syncthreads();
        s[t] += x;
        __syncthreads();
    }
    if (t < nb) bsum[t] = s[t] - v;   // exclusive block offsets
}

__global__ __launch_bounds__(256) void k_scan3(int* __restrict__ rp, const int* __restrict__ bsum, int n) {
    int i = blockIdx.x * blockDim.x + threadIdx.x;
    if (i < n) rp[i + 1] += bsum[i >> 8];
    if (i == 0) rp[0] = 0;
}

// ---------------- precompute bf16 GEMM weight tiles for all layers ----------------
__global__ __launch_bounds__(256) void k_prep_w(const float* __restrict__ Wg_prev,
                                                const float* __restrict__ Wg_succ,
                                                unsigned short* __restrict__ wcat) {
    int idx = blockIdx.x * blockDim.x + threadIdx.x;
    if (idx >= NL * WTN) return;
    int l = idx / WTN;
    int r = idx - l * WTN;
    int n = r / 168, k = r - n * 168;
    float v = 0.f;
    if (k < 72)       v = 0.5f * Wg_prev[(size_t)l * 72 * 64 + k * 64 + n];
    else if (k < 144) v = 0.5f * Wg_succ[(size_t)l * 72 * 64 + (k - 72) * 64 + n];
    wcat[idx] = f2bf(v);
}

// ---------------- scatter: CSR cols + fused edge-embed (fp32) in CSR slot order ----
__global__ __launch_bounds__(256) void k_scatter(const int* __restrict__ prev_src,
                                                 const int* __restrict__ prev_dst,
                                                 const int* __restrict__ tf_src,
                                                 const int* __restrict__ tf_dst,
                                                 const float* __restrict__ xe,
                                                 const float* __restrict__ xef,
                                                 const int* __restrict__ rp,
                                                 int* fill,
                                                 int* colP, int* colS, int* colF,
                                                 float* __restrict__ ePbuf,
                                                 float* __restrict__ eSbuf,
                                                 float* __restrict__ eFbuf,
                                                 const float* __restrict__ Wep, const float* __restrict__ bep,
                                                 const float* __restrict__ Wes, const float* __restrict__ bes,
                                                 const float* __restrict__ Wef, const float* __restrict__ bef) {
    int i = blockIdx.x * blockDim.x + threadIdx.x;
    if (i < NE) {
        int s = prev_src[i], d = prev_dst[i];
        float4 x0 = ((const float4*)xe)[(size_t)i * 2];
        float4 x1 = ((const float4*)xe)[(size_t)i * 2 + 1];
        float x[8] = {x0.x, x0.y, x0.z, x0.w, x1.x, x1.y, x1.z, x1.w};
        float eP[8], eS[8];
#pragma unroll
        for (int j = 0; j < 8; j++) {
            float vp = bep[j], vs = bes[j];
#pragma unroll
            for (int k = 0; k < 8; k++) { vp += x[k] * Wep[k * 8 + j]; vs += x[k] * Wes[k * 8 + j]; }
            eP[j] = elu1(vp); eS[j] = elu1(vs);
        }
        int tP = rp[d] + atomicAdd(&fill[d], 1);
        colP[tP] = s;
        ((float4*)ePbuf)[(size_t)tP * 2]     = make_float4(eP[0], eP[1], eP[2], eP[3]);
        ((float4*)ePbuf)[(size_t)tP * 2 + 1] = make_float4(eP[4], eP[5], eP[6], eP[7]);
        int tS = rp[NI + s] - NE + atomicAdd(&fill[NI + s], 1);
        colS[tS] = d;
        ((float4*)eSbuf)[(size_t)tS * 2]     = make_float4(eS[0], eS[1], eS[2], eS[3]);
        ((float4*)eSbuf)[(size_t)tS * 2 + 1] = make_float4(eS[4], eS[5], eS[6], eS[7]);
    }
    if (i < NEF) {
        int s = tf_src[i], d = tf_dst[i];
        float4 x0 = ((const float4*)xef)[(size_t)i * 2];
        float4 x1 = ((const float4*)xef)[(size_t)i * 2 + 1];
        float x[8] = {x0.x, x0.y, x0.z, x0.w, x1.x, x1.y, x1.z, x1.w};
        float eF[8];
#pragma unroll
        for (int j = 0; j < 8; j++) {
            float v = bef[j];
#pragma unroll
            for (int k = 0; k < 8; k++) v += x[k] * Wef[k * 8 + j];
            eF[j] = elu1(v);
        }
        int tF = rp[2 * NI + d] - 2 * NE + atomicAdd(&fill[2 * NI + d], 1);
        colF[tF] = s;
        ((float4*)eFbuf)[(size_t)tF * 2]     = make_float4(eF[0], eF[1], eF[2], eF[3]);
        ((float4*)eFbuf)[(size_t)tF * 2 + 1] = make_float4(eF[4], eF[5], eF[6], eF[7]);
    }
}

// ---------------- edge-embed aggregation: sequential run-sum per node ----------------
__global__ __launch_bounds__(256) void k_eagg2(const int* __restrict__ rp,
                                               const float* __restrict__ ePbuf,
                                               const float* __restrict__ eSbuf,
                                               const float* __restrict__ eFbuf,
                                               float* __restrict__ aggEp,
                                               float* __restrict__ aggEs,
                                               float* __restrict__ aggEf) {
    int idx = blockIdx.x * blockDim.x + threadIdx.x;
    if (idx >= NT) return;
    const float* buf; float* out; int s, e;
    if (idx < NF) {
        int n = idx;
        s = rp[2 * NI + n] - 2 * NE; e = rp[2 * NI + n + 1] - 2 * NE;
        buf = eFbuf; out = aggEf + (size_t)n * 8;
    } else if (idx < NF + NI) {
        int n = idx - NF;
        s = rp[n]; e = rp[n + 1];
        buf = ePbuf; out = aggEp + (size_t)n * 8;
    } else {
        int n = idx - NF - NI;
        s = rp[NI + n] - NE; e = rp[NI + n + 1] - NE;
        buf = eSbuf; out = aggEs + (size_t)n * 8;
    }
    float a0 = 0.f, a1 = 0.f, a2 = 0.f, a3 = 0.f, a4 = 0.f, a5 = 0.f, a6 = 0.f, a7 = 0.f;
    for (int t = s; t < e; ++t) {
        float4 v0 = ((const float4*)buf)[(size_t)t * 2];
        float4 v1 = ((const float4*)buf)[(size_t)t * 2 + 1];
        a0 += v0.x; a1 += v0.y; a2 += v0.z; a3 += v0.w;
        a4 += v1.x; a5 += v1.y; a6 += v1.z; a7 += v1.w;
    }
    ((float4*)out)[0] = make_float4(a0, a1, a2, a3);
    ((float4*)out)[1] = make_float4(a4, a5, a6, a7);
}

// ---------------- prep X: layer-invariant me-columns + zero pad ----------------
__global__ __launch_bounds__(256) void k_prep_x(const int* __restrict__ rpAll,
                                                const float* __restrict__ aggEp,
                                                const float* __restrict__ aggEs,
                                                unsigned short* __restrict__ X) {
    int i = blockIdx.x * blockDim.x + threadIdx.x;
    if (i >= NI) return;
    int cP = rpAll[i + 1] - rpAll[i];
    int cS = rpAll[NI + i + 1] - rpAll[NI + i];
    float invP = 1.f / (float)max(cP, 1);
    float invS = 1.f / (float)max(cS, 1);
    unsigned short* xr = X + (size_t)i * KX;
#pragma unroll
    for (int c = 0; c < 2; c++) {
        float4 ep = ((const float4*)(aggEp + (size_t)i * 8))[c];
        float4 es = ((const float4*)(aggEs + (size_t)i * 8))[c];
        ushort4 up; up.x = f2bf(ep.x * invP); up.y = f2bf(ep.y * invP);
                    up.z = f2bf(ep.z * invP); up.w = f2bf(ep.w * invP);
        ushort4 us; us.x = f2bf(es.x * invS); us.y = f2bf(es.y * invS);
                    us.z = f2bf(es.z * invS); us.w = f2bf(es.w * invS);
        ((ushort4*)(xr + 64))[c]  = up;
        ((ushort4*)(xr + 136))[c] = us;
    }
    ushort4 z; z.x = z.y = z.z = z.w = 0;
#pragma unroll
    for (int c = 0; c < 4; c++) ((ushort4*)(xr + 144))[c] = z;
}

// ---------------- node embedding (wave per node, lane = output feature) ----------------
__global__ __launch_bounds__(256) void k_node_embed(const float* __restrict__ xi,
                                                    const float* __restrict__ xf,
                                                    const float* __restrict__ Wit, const float* __restrict__ bit,
                                                    const float* __restrict__ Wft, const float* __restrict__ bft,
                                                    float* __restrict__ inst, unsigned short* __restrict__ inst_bf,
                                                    float* __restrict__ fin) {
    const int NPW = 16;
    int lane = threadIdx.x & 63;
    int wave = (blockIdx.x * blockDim.x + threadIdx.x) >> 6;
    int base = wave * NPW;
    float wi[DN], wf[DN];
#pragma unroll
    for (int k = 0; k < DN; k++) { wi[k] = Wit[k * 64 + lane]; wf[k] = Wft[k * 64 + lane]; }
    float bi = bit[lane], bf = bft[lane];
    for (int n = 0; n < NPW; n++) {
        int i = base + n;
        if (i < NI) {
            const float4* x4 = (const float4*)(xi + (size_t)i * DN);
            float4 xa = x4[0], xb = x4[1], xc = x4[2], xd = x4[3];
            float x[DN] = {xa.x, xa.y, xa.z, xa.w, xb.x, xb.y, xb.z, xb.w,
                           xc.x, xc.y, xc.z, xc.w, xd.x, xd.y, xd.z, xd.w};
            float acc = bi;
#pragma unroll
            for (int k = 0; k < DN; k++) acc += x[k] * wi[k];
            float v = elu1(acc);
            inst[(size_t)i * 64 + lane] = v;
            inst_bf[(size_t)i * 64 + lane] = f2bf(v);
        } else if (i < NI + NF) {
            int f = i - NI;
            const float4* x4 = (const float4*)(xf + (size_t)f * DN);
            float4 xa = x4[0], xb = x4[1], xc = x4[2], xd = x4[3];
            float x[DN] = {xa.x, xa.y, xa.z, xa.w, xb.x, xb.y, xb.z, xb.w,
                           xc.x, xc.y, xc.z, xc.w, xd.x, xd.y, xd.z, xd.w};
            float acc = bf;
#pragma unroll
            for (int k = 0; k < DN; k++) acc += x[k] * wf[k];
            fin[(size_t)f * 64 + lane] = elu1(acc);
        }
    }
}

// ---------------- SpMM (gather-mean over bf16 rows), 8 tasks per wave ----------------
// lane = (task-slot n3 = lane>>3, feature-oct f8 = lane&7). Each 8-lane slot owns
// one node-direction task; each lane loads bf16x8 (16B) -> one vmem instruction
// gathers 8 rows x 128B = 1KB. fp32 accumulation in strictly ascending CSR order.
// F tasks first. No cross-lane ops.
__global__ __launch_bounds__(256) void k_spmm(const unsigned short* __restrict__ inst_bf,
                                              const int* __restrict__ rp,
                                              const int* __restrict__ colP,
                                              const int* __restrict__ colS,
                                              const int* __restrict__ colF,
                                              unsigned short* __restrict__ X,
                                              float* __restrict__ aggHf) {
    int lane = threadIdx.x & 63;
    int wv = (blockIdx.x * blockDim.x + threadIdx.x) >> 6;
    int n3 = lane >> 3;       // task slot 0..7
    int f8 = lane & 7;        // feature oct
    int task = wv * 8 + n3;
    if (task >= NT) return;   // per-lane exit; no cross-lane ops below

    const int* col; int i, rbase, ebase, xoff;
    if (task < NF)            { i = task;           rbase = 2 * NI; ebase = 2 * NE; col = colF; xoff = -1; }
    else if (task < NF + NI)  { i = task - NF;      rbase = 0;      ebase = 0;      col = colP; xoff = 0;  }
    else                      { i = task - NF - NI; rbase = NI;     ebase = NE;     col = colS; xoff = 72; }

    int s = rp[rbase + i] - ebase, e1 = rp[rbase + i + 1] - ebase;
    const unsigned short* src = inst_bf + f8 * 8;
    float a[8];
#pragma unroll
    for (int j = 0; j < 8; j++) a[j] = 0.f;

    int pos = s;
    for (; pos + 8 <= e1; pos += 8) {            // 8 independent 16B gathers in flight
        int c[8];
#pragma unroll
        for (int u = 0; u < 8; u++) c[u] = col[pos + u];
        bf16x8 v[8];
#pragma unroll
        for (int u = 0; u < 8; u++) v[u] = *(const bf16x8*)(src + (size_t)c[u] * 64);
#pragma unroll
        for (int u = 0; u < 8; u++) {
#pragma unroll
            for (int j = 0; j < 8; j++) a[j] += bf2f((unsigned short)v[u][j]);
        }
    }
    for (; pos + 4 <= e1; pos += 4) {            // 4-deep
        int c0 = col[pos], c1 = col[pos + 1], c2 = col[pos + 2], c3 = col[pos + 3];
        bf16x8 v0 = *(const bf16x8*)(src + (size_t)c0 * 64);
        bf16x8 v1 = *(const bf16x8*)(src + (size_t)c1 * 64);
        bf16x8 v2 = *(const bf16x8*)(src + (size_t)c2 * 64);
        bf16x8 v3 = *(const bf16x8*)(src + (size_t)c3 * 64);
#pragma unroll
        for (int j = 0; j < 8; j++) a[j] += bf2f((unsigned short)v0[j]);
#pragma unroll
        for (int j = 0; j < 8; j++) a[j] += bf2f((unsigned short)v1[j]);
#pragma unroll
        for (int j = 0; j < 8; j++) a[j] += bf2f((unsigned short)v2[j]);
#pragma unroll
        for (int j = 0; j < 8; j++) a[j] += bf2f((unsigned short)v3[j]);
    }
    for (; pos < e1; ++pos) {                    // tail, order preserved
        int c = col[pos];
        bf16x8 v = *(const bf16x8*)(src + (size_t)c * 64);
#pragma unroll
        for (int j = 0; j < 8; j++) a[j] += bf2f((unsigned short)v[j]);
    }

    int cnt = e1 - s;
    float inv = cnt > 0 ? 1.f / (float)cnt : 0.f;
    if (xoff >= 0) {
        ushort4 o0, o1;
        o0.x = f2bf(a[0] * inv); o0.y = f2bf(a[1] * inv);
        o0.z = f2bf(a[2] * inv); o0.w = f2bf(a[3] * inv);
        o1.x = f2bf(a[4] * inv); o1.y = f2bf(a[5] * inv);
        o1.z = f2bf(a[6] * inv); o1.w = f2bf(a[7] * inv);
        unsigned short* dst = X + (size_t)i * KX + xoff + f8 * 8;
        *(ushort4*)dst = o0;
        *(ushort4*)(dst + 4) = o1;
    } else {
        float* dst = aggHf + (size_t)i * 64 + f8 * 8;
        *(float4*)dst = make_float4(a[0] * inv, a[1] * inv, a[2] * inv, a[3] * inv);
        *(float4*)(dst + 4) = make_float4(a[4] * inv, a[5] * inv, a[6] * inv, a[7] * inv);
    }
}

// ---------------- per-layer dense update: inst MFMA GEMM blocks + fin blocks ----------------
// No LDS at all: A-fragments from global X, B-fragments directly from precomputed
// global wcat_l (same bf16 bytes as the old LDS tile -> bit-identical MFMA; all
// blocks share the 21KB tile through L2). Higher occupancy than LDS-staged variant.
__global__ __launch_bounds__(256) void k_dense_layer(
    const unsigned short* __restrict__ X,
    float* __restrict__ inst, unsigned short* __restrict__ inst_bf,
    const int* __restrict__ rpAll,
    const unsigned short* __restrict__ wcat_l,
    const float* __restrict__ bp, const float* __restrict__ bs,
    float* __restrict__ fin,
    const float* __restrict__ aggHf, const float* __restrict__ aggEf,
    const float* __restrict__ Wf, const float* __restrict__ bf) {
    int t = threadIdx.x;

    if (blockIdx.x < NBI) {
        // ---------- instruction-node GEMM path ----------
        int wave = t >> 6, lane = t & 63;
        int rowbase = blockIdx.x * 128 + wave * 32;   // this wave's 32 rows
        int lrow = lane & 15, lk = (lane >> 4) * 8;

        f32x4 acc[2][4];
#pragma unroll
        for (int rb = 0; rb < 2; rb++)
#pragma unroll
            for (int nb = 0; nb < 4; nb++) acc[rb][nb] = (f32x4){0.f, 0.f, 0.f, 0.f};

#pragma unroll
        for (int kc = 0; kc < 5; kc++) {
            int k0 = kc * 32 + lk;
            bf16x8 a[2], b[4];
#pragma unroll
            for (int rb = 0; rb < 2; rb++) {
                int r = min(rowbase + rb * 16 + lrow, NI - 1);
                a[rb] = *(const bf16x8*)(X + (size_t)r * KX + k0);
            }
#pragma unroll
            for (int nb = 0; nb < 4; nb++)
                b[nb] = *(const bf16x8*)(wcat_l + (size_t)(nb * 16 + lrow) * 168 + k0);
#pragma unroll
            for (int rb = 0; rb < 2; rb++)
#pragma unroll
                for (int nb = 0; nb < 4; nb++)
                    acc[rb][nb] = __builtin_amdgcn_mfma_f32_16x16x32_bf16(a[rb], b[nb], acc[rb][nb], 0, 0, 0);
        }

        // epilogue: C[row= (lane>>4)*4+j, col= nb*16 + (lane&15)]
#pragma unroll
        for (int rb = 0; rb < 2; rb++) {
#pragma unroll
            for (int j = 0; j < 4; j++) {
                int node = rowbase + rb * 16 + (lane >> 4) * 4 + j;
                bool v = node < NI;
                int nn = v ? node : NI - 1;
                float mP = (v && (rpAll[nn + 1] > rpAll[nn])) ? 0.5f : 0.f;
                float mS = (v && (rpAll[NI + nn + 1] > rpAll[NI + nn])) ? 0.5f : 0.f;
#pragma unroll
                for (int nb = 0; nb < 4; nb++) {
                    int col = nb * 16 + lrow;
                    float x = inst[(size_t)nn * 64 + col] + acc[rb][nb][j] + mP * bp[col] + mS * bs[col];
                    x = elu1(x);
                    if (v) {
                        inst[(size_t)nn * 64 + col] = x;
                        inst_bf[(size_t)nn * 64 + col] = f2bf(x);
                    }
                }
            }
        }
    } else {
        // ---------- final-node path: thread = (node, j-quad) ----------
        int tid = (blockIdx.x - NBI) * 256 + t;     // 0 .. 31999
        int n = tid >> 4;                           // node 0..1999
        int jq = tid & 15;                          // j-quad 0..15
        const int* rpF = rpAll + 2 * NI;
        int cF = rpF[n + 1] - rpF[n];
        float mF = (cF > 0) ? 1.f : 0.f;
        float invF = 1.f / (float)max(cF, 1);

        float acc0 = bf[jq * 4 + 0], acc1 = bf[jq * 4 + 1];
        float acc2 = bf[jq * 4 + 2], acc3 = bf[jq * 4 + 3];
        const float* hrow = aggHf + (size_t)n * 64;
        for (int k = 0; k < 64; k++) {
            float h = hrow[k];
            float4 w = *(const float4*)(Wf + (size_t)k * 64 + jq * 4);
            acc0 += h * w.x; acc1 += h * w.y; acc2 += h * w.z; acc3 += h * w.w;
        }
        const float* erow = aggEf + (size_t)n * 8;
#pragma unroll
        for (int k = 0; k < 8; k++) {
            float h = erow[k] * invF;
            float4 w = *(const float4*)(Wf + (size_t)(64 + k) * 64 + jq * 4);
            acc0 += h * w.x; acc1 += h * w.y; acc2 += h * w.z; acc3 += h * w.w;
        }
        float4 fv = *(const float4*)(fin + (size_t)n * 64 + jq * 4);
        float4 o;
        o.x = elu1(fv.x + mF * acc0);
        o.y = elu1(fv.y + mF * acc1);
        o.z = elu1(fv.z + mF * acc2);
        o.w = elu1(fv.w + mF * acc3);
        *(float4*)(fin + (size_t)n * 64 + jq * 4) = o;
    }
}

// ---------------- readout head ----------------
__global__ __launch_bounds__(64, 1) void k_head(
    const float* __restrict__ fin,
    const float* __restrict__ Wr1, const float* __restrict__ br1,
    const float* __restrict__ Wr2, const float* __restrict__ br2,
    const float* __restrict__ Wr3, const float* __restrict__ br3,
    float* __restrict__ out) {
    __shared__ float hL[64 * 65];
    const int lane = threadIdx.x;
    const int base = blockIdx.x * 64;

    for (int idx = lane; idx < 1024; idx += 64) {
        int n = idx >> 4, k4 = idx & 15;
        float4 v = ((const float4*)fin)[(size_t)min(base + n, NF - 1) * 16 + k4];
        float* d = &hL[n * 65 + k4 * 4];
        d[0] = v.x; d[1] = v.y; d[2] = v.z; d[3] = v.w;
    }
    __syncthreads();

    float acc[64];
#pragma unroll
    for (int j = 0; j < 64; j++) acc[j] = br1[j];
#pragma unroll 4
    for (int k = 0; k < 64; k++) {
        float h = hL[lane * 65 + k];
#pragma unroll
        for (int j = 0; j < 64; j++) acc[j] += h * Wr1[k * 64 + j];
    }
#pragma unroll
    for (int j = 0; j < 64; j++) hL[lane * 65 + j] = elu1(acc[j]);

#pragma unroll
    for (int j = 0; j < 64; j++) acc[j] = br2[j];
#pragma unroll 4
    for (int k = 0; k < 64; k++) {
        float h = hL[lane * 65 + k];
#pragma unroll
        for (int j = 0; j < 64; j++) acc[j] += h * Wr2[k * 64 + j];
    }
    float r = br3[0];
#pragma unroll
    for (int j = 0; j < 64; j++) r += elu1(acc[j]) * Wr3[j];

    int i = base + lane;
    if (i < NF) out[i] = r;
}

extern "C" void kernel_launch(void* const* d_in, const int* in_sizes, int n_in,
                              void* d_out, int out_size, void* d_ws, size_t ws_size,
                              hipStream_t stream) {
    const float* xi  = (const float*)d_in[0];
    const float* xf  = (const float*)d_in[1];
    const float* xe  = (const float*)d_in[2];
    const float* xef = (const float*)d_in[3];
    const int* prev_src = (const int*)d_in[4];
    const int* prev_dst = (const int*)d_in[5];
    const int* tf_src = (const int*)d_in[6];
    const int* tf_dst = (const int*)d_in[7];
    const float* W_it = (const float*)d_in[8];  const float* b_it = (const float*)d_in[9];
    const float* W_ft = (const float*)d_in[10]; const float* b_ft = (const float*)d_in[11];
    const float* W_ep = (const float*)d_in[12]; const float* b_ep = (const float*)d_in[13];
    const float* W_es = (const float*)d_in[14]; const float* b_es = (const float*)d_in[15];
    const float* W_ef = (const float*)d_in[16]; const float* b_ef = (const float*)d_in[17];
    const float* Wg_prev = (const float*)d_in[18]; const float* bg_prev = (const float*)d_in[19];
    const float* Wg_succ = (const float*)d_in[20]; const float* bg_succ = (const float*)d_in[21];
    const float* Wg_tf   = (const float*)d_in[22]; const float* bg_tf   = (const float*)d_in[23];
    const float* Wr1 = (const float*)d_in[24]; const float* br1 = (const float*)d_in[25];
    const float* Wr2 = (const float*)d_in[26]; const float* br2 = (const float*)d_in[27];
    const float* Wr3 = (const float*)d_in[28]; const float* br3 = (const float*)d_in[29];

    char* ws = (char*)d_ws;
    size_t off = 0;
    auto alloc = [&](size_t bytes) -> char* {
        char* p = ws + off;
        off += (bytes + 255) & ~(size_t)255;
        return p;
    };
    float* inst  = (float*)alloc((size_t)NI * 64 * 4);
    unsigned short* inst_bf = (unsigned short*)alloc((size_t)NI * 64 * 2);
    unsigned short* X = (unsigned short*)alloc((size_t)NI * KX * 2);
    float* fin   = (float*)alloc((size_t)NF * 64 * 4);
    float* aggHf = (float*)alloc((size_t)NF * 64 * 4);
    float* aggEp = (float*)alloc((size_t)NI * 8 * 4);
    float* aggEs = (float*)alloc((size_t)NI * 8 * 4);
    float* aggEf = (float*)alloc((size_t)NF * 8 * 4);
    unsigned short* wcat = (unsigned short*)alloc((size_t)NL * WTN * 2);
    char* zero_begin = ws + off;
    int* cnt  = (int*)alloc((size_t)NT * 4);
    int* fill = (int*)alloc((size_t)NT * 4);
    char* zero_end = ws + off;
    int* rpAll = (int*)alloc((size_t)(NT + 1) * 4);
    int* colP = (int*)alloc((size_t)NE * 4);
    int* colS = (int*)alloc((size_t)NE * 4);
    int* colF = (int*)alloc((size_t)NEF * 4);
    int* bsum = (int*)alloc(1024 * 4);
    (void)ws_size; (void)in_sizes; (void)n_in; (void)out_size;

    // scatter-stage fp32 edge-embed buffers alias regions dead until after k_eagg2:
    //   ePbuf (NE*32B = 25.6MB)  -> X (32MB, live cols written by k_prep_x/spmm later)
    //   eSbuf (NE*32B = 25.6MB)  -> inst (25.6MB, first written by k_node_embed)
    //   eFbuf (NEF*32B = 6.4MB)  -> inst_bf (12.8MB, first written by k_node_embed)
    float* ePbuf = (float*)X;
    float* eSbuf = inst;
    float* eFbuf = (float*)inst_bf;

    hipMemsetAsync(zero_begin, 0, (size_t)(zero_end - zero_begin), stream);

    k_prep_w<<<(NL * WTN + 255) / 256, 256, 0, stream>>>(Wg_prev, Wg_succ, wcat);

    k_count<<<(NE + 255) / 256, 256, 0, stream>>>(prev_src, prev_dst, tf_dst, cnt);

    int nb = (NT + 255) / 256;
    k_scan1<<<nb, 256, 0, stream>>>(cnt, NT, rpAll, bsum);
    k_scan2<<<1, 1024, 0, stream>>>(bsum, nb);
    k_scan3<<<nb, 256, 0, stream>>>(rpAll, bsum, NT);

    k_scatter<<<(NE + 255) / 256, 256, 0, stream>>>(prev_src, prev_dst, tf_src, tf_dst,
                                                    xe, xef, rpAll, fill,
                                                    colP, colS, colF,
                                                    ePbuf, eSbuf, eFbuf,
                                                    W_ep, b_ep, W_es, b_es, W_ef, b_ef);

    k_eagg2<<<(NT + 255) / 256, 256, 0, stream>>>(rpAll, ePbuf, eSbuf, eFbuf,
                                                  aggEp, aggEs, aggEf);

    k_prep_x<<<(NI + 255) / 256, 256, 0, stream>>>(rpAll, aggEp, aggEs, X);

    {
        int waves = (NI + NF + 15) / 16;
        int blocks = (waves + 3) / 4;
        k_node_embed<<<blocks, 256, 0, stream>>>(xi, xf, W_it, b_it, W_ft, b_ft,
                                                 inst, inst_bf, fin);
    }

    for (int l = 0; l < NL; l++) {
        // 8 tasks per wave, 32 tasks per 256-thread block; F tasks first
        k_spmm<<<(NT + 31) / 32, 256, 0, stream>>>(inst_bf, rpAll,
                                                   colP, colS, colF,
                                                   X, aggHf);
        k_dense_layer<<<NBI + NBF, 256, 0, stream>>>(X, inst, inst_bf, rpAll,
                                                     wcat + (size_t)l * WTN,
                                                     bg_prev + (size_t)l * 64, bg_succ + (size_t)l * 64,
                                                     fin, aggHf, aggEf,
                                                     Wg_tf + (size_t)l * 72 * 64, bg_tf + (size_t)l * 64);
    }

    k_head<<<(NF + 63) / 64, 64, 0, stream>>>(fin, Wr1, br1, Wr2, br2, Wr3, br3, (float*)d_out);
}

// Round 15
// 1016.917 us; speedup vs baseline: 2.2851x; 1.0670x over previous
//
#include <hip/hip_runtime.h>
#include <math.h>

#define NI 100000
#define NF 2000
#define NE 800000
#define NEF 200000
#define DN 16
#define NL 11
#define NT (2 * NI + NF)   // concatenated node-direction count: P | S | F
#define KX 160             // padded K stride of X (bf16): 64 P | 8 meP | 64 S | 8 meS | 16 zero
#define NBI 782            // inst GEMM blocks: ceil(NI/128)
#define NBF 125            // fin blocks: NF*16/256
#define WTN (64 * 168)     // wcat tile elements per layer

typedef short bf16x8 __attribute__((ext_vector_type(8)));
typedef float f32x4 __attribute__((ext_vector_type(4)));

__device__ __forceinline__ float elu1(float x) { return x > 0.f ? x : expm1f(x); }

__device__ __forceinline__ unsigned short f2bf(float f) {
    unsigned x = __float_as_uint(f);
    return (unsigned short)((x + 0x7fffu + ((x >> 16) & 1u)) >> 16);
}
__device__ __forceinline__ float bf2f(unsigned short u) {
    return __uint_as_float(((unsigned)u) << 16);
}

// ---------------- CSR build (concatenated P|S|F degree array) ----------------
__global__ __launch_bounds__(256) void k_count(const int* __restrict__ prev_src,
                                               const int* __restrict__ prev_dst,
                                               const int* __restrict__ tf_dst,
                                               int* cnt) {
    int i = blockIdx.x * blockDim.x + threadIdx.x;
    if (i < NE) {
        atomicAdd(&cnt[prev_dst[i]], 1);
        atomicAdd(&cnt[NI + prev_src[i]], 1);
    }
    if (i < NEF) atomicAdd(&cnt[2 * NI + tf_dst[i]], 1);
}

__global__ __launch_bounds__(256) void k_scan1(const int* __restrict__ cnt, int n,
                                               int* __restrict__ rp, int* __restrict__ bsum) {
    __shared__ int s[256];
    int t = threadIdx.x, b = blockIdx.x, i = b * 256 + t;
    int v = (i < n) ? cnt[i] : 0;
    s[t] = v; __syncthreads();
    for (int o = 1; o < 256; o <<= 1) {
        int x = (t >= o) ? s[t - o] : 0;
        __syncthreads();
        s[t] += x;
        __syncthreads();
    }
    if (i < n) rp[i + 1] = s[t];
    if (t == 255) bsum[b] = s[255];
}

__global__ __launch_bounds__(1024) void k_scan2(int* __restrict__ bsum, int nb) {
    __shared__ int s[1024];
    int t = threadIdx.x;
    int v = (t < nb) ? bsum[t] : 0;
    s[t] = v; __syncthreads();
    for (int o = 1; o < 1024; o <<= 1) {
        int x = (t >= o) ? s[t - o] : 0;
        __syncthreads();
        s[t] += x;
        __syncthreads();
    }
    if (t < nb) bsum[t] = s[t] - v;   // exclusive block offsets
}

__global__ __launch_bounds__(256) void k_scan3(int* __restrict__ rp, const int* __restrict__ bsum, int n) {
    int i = blockIdx.x * blockDim.x + threadIdx.x;
    if (i < n) rp[i + 1] += bsum[i >> 8];
    if (i == 0) rp[0] = 0;
}

// ---------------- precompute bf16 GEMM weight tiles for all layers ----------------
__global__ __launch_bounds__(256) void k_prep_w(const float* __restrict__ Wg_prev,
                                                const float* __restrict__ Wg_succ,
                                                unsigned short* __restrict__ wcat) {
    int idx = blockIdx.x * blockDim.x + threadIdx.x;
    if (idx >= NL * WTN) return;
    int l = idx / WTN;
    int r = idx - l * WTN;
    int n = r / 168, k = r - n * 168;
    float v = 0.f;
    if (k < 72)       v = 0.5f * Wg_prev[(size_t)l * 72 * 64 + k * 64 + n];
    else if (k < 144) v = 0.5f * Wg_succ[(size_t)l * 72 * 64 + (k - 72) * 64 + n];
    wcat[idx] = f2bf(v);
}

// ---------------- scatter: CSR cols + fused edge-embed (fp32) in CSR slot order ----
__global__ __launch_bounds__(256) void k_scatter(const int* __restrict__ prev_src,
                                                 const int* __restrict__ prev_dst,
                                                 const int* __restrict__ tf_src,
                                                 const int* __restrict__ tf_dst,
                                                 const float* __restrict__ xe,
                                                 const float* __restrict__ xef,
                                                 const int* __restrict__ rp,
                                                 int* fill,
                                                 int* colP, int* colS, int* colF,
                                                 float* __restrict__ ePbuf,
                                                 float* __restrict__ eSbuf,
                                                 float* __restrict__ eFbuf,
                                                 const float* __restrict__ Wep, const float* __restrict__ bep,
                                                 const float* __restrict__ Wes, const float* __restrict__ bes,
                                                 const float* __restrict__ Wef, const float* __restrict__ bef) {
    int i = blockIdx.x * blockDim.x + threadIdx.x;
    if (i < NE) {
        int s = prev_src[i], d = prev_dst[i];
        float4 x0 = ((const float4*)xe)[(size_t)i * 2];
        float4 x1 = ((const float4*)xe)[(size_t)i * 2 + 1];
        float x[8] = {x0.x, x0.y, x0.z, x0.w, x1.x, x1.y, x1.z, x1.w};
        float eP[8], eS[8];
#pragma unroll
        for (int j = 0; j < 8; j++) {
            float vp = bep[j], vs = bes[j];
#pragma unroll
            for (int k = 0; k < 8; k++) { vp += x[k] * Wep[k * 8 + j]; vs += x[k] * Wes[k * 8 + j]; }
            eP[j] = elu1(vp); eS[j] = elu1(vs);
        }
        int tP = rp[d] + atomicAdd(&fill[d], 1);
        colP[tP] = s;
        ((float4*)ePbuf)[(size_t)tP * 2]     = make_float4(eP[0], eP[1], eP[2], eP[3]);
        ((float4*)ePbuf)[(size_t)tP * 2 + 1] = make_float4(eP[4], eP[5], eP[6], eP[7]);
        int tS = rp[NI + s] - NE + atomicAdd(&fill[NI + s], 1);
        colS[tS] = d;
        ((float4*)eSbuf)[(size_t)tS * 2]     = make_float4(eS[0], eS[1], eS[2], eS[3]);
        ((float4*)eSbuf)[(size_t)tS * 2 + 1] = make_float4(eS[4], eS[5], eS[6], eS[7]);
    }
    if (i < NEF) {
        int s = tf_src[i], d = tf_dst[i];
        float4 x0 = ((const float4*)xef)[(size_t)i * 2];
        float4 x1 = ((const float4*)xef)[(size_t)i * 2 + 1];
        float x[8] = {x0.x, x0.y, x0.z, x0.w, x1.x, x1.y, x1.z, x1.w};
        float eF[8];
#pragma unroll
        for (int j = 0; j < 8; j++) {
            float v = bef[j];
#pragma unroll
            for (int k = 0; k < 8; k++) v += x[k] * Wef[k * 8 + j];
            eF[j] = elu1(v);
        }
        int tF = rp[2 * NI + d] - 2 * NE + atomicAdd(&fill[2 * NI + d], 1);
        colF[tF] = s;
        ((float4*)eFbuf)[(size_t)tF * 2]     = make_float4(eF[0], eF[1], eF[2], eF[3]);
        ((float4*)eFbuf)[(size_t)tF * 2 + 1] = make_float4(eF[4], eF[5], eF[6], eF[7]);
    }
}

// ---------------- edge-embed aggregation: 8 tasks/wave, lane = feature ----------------
// lane f8 owns one feature of its task: reads buf[t*8+f8] for t ascending — the
// 8 lanes of a slot cover one coalesced 32B record per step. Per-feature add
// order identical to the old serial version -> bit-identical. F tasks first.
__global__ __launch_bounds__(256) void k_eagg2(const int* __restrict__ rp,
                                               const float* __restrict__ ePbuf,
                                               const float* __restrict__ eSbuf,
                                               const float* __restrict__ eFbuf,
                                               float* __restrict__ aggEp,
                                               float* __restrict__ aggEs,
                                               float* __restrict__ aggEf) {
    int lane = threadIdx.x & 63;
    int wv = (blockIdx.x * blockDim.x + threadIdx.x) >> 6;
    int n3 = lane >> 3;       // task slot 0..7
    int f8 = lane & 7;        // feature
    int idx = wv * 8 + n3;
    if (idx >= NT) return;

    const float* buf; float* out; int s, e;
    if (idx < NF) {
        int n = idx;
        s = rp[2 * NI + n] - 2 * NE; e = rp[2 * NI + n + 1] - 2 * NE;
        buf = eFbuf; out = aggEf + (size_t)n * 8;
    } else if (idx < NF + NI) {
        int n = idx - NF;
        s = rp[n]; e = rp[n + 1];
        buf = ePbuf; out = aggEp + (size_t)n * 8;
    } else {
        int n = idx - NF - NI;
        s = rp[NI + n] - NE; e = rp[NI + n + 1] - NE;
        buf = eSbuf; out = aggEs + (size_t)n * 8;
    }
    const float* src = buf + f8;
    float a = 0.f;
    int t = s;
    for (; t + 4 <= e; t += 4) {
        float v0 = src[(size_t)t * 8];
        float v1 = src[(size_t)(t + 1) * 8];
        float v2 = src[(size_t)(t + 2) * 8];
        float v3 = src[(size_t)(t + 3) * 8];
        a += v0; a += v1; a += v2; a += v3;
    }
    for (; t < e; ++t) a += src[(size_t)t * 8];
    out[f8] = a;
}

// ---------------- prep X: layer-invariant me-columns + zero pad ----------------
__global__ __launch_bounds__(256) void k_prep_x(const int* __restrict__ rpAll,
                                                const float* __restrict__ aggEp,
                                                const float* __restrict__ aggEs,
                                                unsigned short* __restrict__ X) {
    int i = blockIdx.x * blockDim.x + threadIdx.x;
    if (i >= NI) return;
    int cP = rpAll[i + 1] - rpAll[i];
    int cS = rpAll[NI + i + 1] - rpAll[NI + i];
    float invP = 1.f / (float)max(cP, 1);
    float invS = 1.f / (float)max(cS, 1);
    unsigned short* xr = X + (size_t)i * KX;
#pragma unroll
    for (int c = 0; c < 2; c++) {
        float4 ep = ((const float4*)(aggEp + (size_t)i * 8))[c];
        float4 es = ((const float4*)(aggEs + (size_t)i * 8))[c];
        ushort4 up; up.x = f2bf(ep.x * invP); up.y = f2bf(ep.y * invP);
                    up.z = f2bf(ep.z * invP); up.w = f2bf(ep.w * invP);
        ushort4 us; us.x = f2bf(es.x * invS); us.y = f2bf(es.y * invS);
                    us.z = f2bf(es.z * invS); us.w = f2bf(es.w * invS);
        ((ushort4*)(xr + 64))[c]  = up;
        ((ushort4*)(xr + 136))[c] = us;
    }
    ushort4 z; z.x = z.y = z.z = z.w = 0;
#pragma unroll
    for (int c = 0; c < 4; c++) ((ushort4*)(xr + 144))[c] = z;
}

// ---------------- node embedding (wave per node, lane = output feature) ----------------
__global__ __launch_bounds__(256) void k_node_embed(const float* __restrict__ xi,
                                                    const float* __restrict__ xf,
                                                    const float* __restrict__ Wit, const float* __restrict__ bit,
                                                    const float* __restrict__ Wft, const float* __restrict__ bft,
                                                    float* __restrict__ inst, unsigned short* __restrict__ inst_bf,
                                                    float* __restrict__ fin) {
    const int NPW = 16;
    int lane = threadIdx.x & 63;
    int wave = (blockIdx.x * blockDim.x + threadIdx.x) >> 6;
    int base = wave * NPW;
    float wi[DN], wf[DN];
#pragma unroll
    for (int k = 0; k < DN; k++) { wi[k] = Wit[k * 64 + lane]; wf[k] = Wft[k * 64 + lane]; }
    float bi = bit[lane], bf = bft[lane];
    for (int n = 0; n < NPW; n++) {
        int i = base + n;
        if (i < NI) {
            const float4* x4 = (const float4*)(xi + (size_t)i * DN);
            float4 xa = x4[0], xb = x4[1], xc = x4[2], xd = x4[3];
            float x[DN] = {xa.x, xa.y, xa.z, xa.w, xb.x, xb.y, xb.z, xb.w,
                           xc.x, xc.y, xc.z, xc.w, xd.x, xd.y, xd.z, xd.w};
            float acc = bi;
#pragma unroll
            for (int k = 0; k < DN; k++) acc += x[k] * wi[k];
            float v = elu1(acc);
            inst[(size_t)i * 64 + lane] = v;
            inst_bf[(size_t)i * 64 + lane] = f2bf(v);
        } else if (i < NI + NF) {
            int f = i - NI;
            const float4* x4 = (const float4*)(xf + (size_t)f * DN);
            float4 xa = x4[0], xb = x4[1], xc = x4[2], xd = x4[3];
            float x[DN] = {xa.x, xa.y, xa.z, xa.w, xb.x, xb.y, xb.z, xb.w,
                           xc.x, xc.y, xc.z, xc.w, xd.x, xd.y, xd.z, xd.w};
            float acc = bf;
#pragma unroll
            for (int k = 0; k < DN; k++) acc += x[k] * wf[k];
            fin[(size_t)f * 64 + lane] = elu1(acc);
        }
    }
}

// ---------------- SpMM (gather-mean over bf16 rows), 8 tasks per wave ----------------
__global__ __launch_bounds__(256) void k_spmm(const unsigned short* __restrict__ inst_bf,
                                              const int* __restrict__ rp,
                                              const int* __restrict__ colP,
                                              const int* __restrict__ colS,
                                              const int* __restrict__ colF,
                                              unsigned short* __restrict__ X,
                                              float* __restrict__ aggHf) {
    int lane = threadIdx.x & 63;
    int wv = (blockIdx.x * blockDim.x + threadIdx.x) >> 6;
    int n3 = lane >> 3;       // task slot 0..7
    int f8 = lane & 7;        // feature oct
    int task = wv * 8 + n3;
    if (task >= NT) return;   // per-lane exit; no cross-lane ops below

    const int* col; int i, rbase, ebase, xoff;
    if (task < NF)            { i = task;           rbase = 2 * NI; ebase = 2 * NE; col = colF; xoff = -1; }
    else if (task < NF + NI)  { i = task - NF;      rbase = 0;      ebase = 0;      col = colP; xoff = 0;  }
    else                      { i = task - NF - NI; rbase = NI;     ebase = NE;     col = colS; xoff = 72; }

    int s = rp[rbase + i] - ebase, e1 = rp[rbase + i + 1] - ebase;
    const unsigned short* src = inst_bf + f8 * 8;
    float a[8];
#pragma unroll
    for (int j = 0; j < 8; j++) a[j] = 0.f;

    int pos = s;
    for (; pos + 8 <= e1; pos += 8) {            // 8 independent 16B gathers in flight
        int c[8];
#pragma unroll
        for (int u = 0; u < 8; u++) c[u] = col[pos + u];
        bf16x8 v[8];
#pragma unroll
        for (int u = 0; u < 8; u++) v[u] = *(const bf16x8*)(src + (size_t)c[u] * 64);
#pragma unroll
        for (int u = 0; u < 8; u++) {
#pragma unroll
            for (int j = 0; j < 8; j++) a[j] += bf2f((unsigned short)v[u][j]);
        }
    }
    for (; pos + 4 <= e1; pos += 4) {            // 4-deep
        int c0 = col[pos], c1 = col[pos + 1], c2 = col[pos + 2], c3 = col[pos + 3];
        bf16x8 v0 = *(const bf16x8*)(src + (size_t)c0 * 64);
        bf16x8 v1 = *(const bf16x8*)(src + (size_t)c1 * 64);
        bf16x8 v2 = *(const bf16x8*)(src + (size_t)c2 * 64);
        bf16x8 v3 = *(const bf16x8*)(src + (size_t)c3 * 64);
#pragma unroll
        for (int j = 0; j < 8; j++) a[j] += bf2f((unsigned short)v0[j]);
#pragma unroll
        for (int j = 0; j < 8; j++) a[j] += bf2f((unsigned short)v1[j]);
#pragma unroll
        for (int j = 0; j < 8; j++) a[j] += bf2f((unsigned short)v2[j]);
#pragma unroll
        for (int j = 0; j < 8; j++) a[j] += bf2f((unsigned short)v3[j]);
    }
    for (; pos < e1; ++pos) {                    // tail, order preserved
        int c = col[pos];
        bf16x8 v = *(const bf16x8*)(src + (size_t)c * 64);
#pragma unroll
        for (int j = 0; j < 8; j++) a[j] += bf2f((unsigned short)v[j]);
    }

    int cnt = e1 - s;
    float inv = cnt > 0 ? 1.f / (float)cnt : 0.f;
    if (xoff >= 0) {
        ushort4 o0, o1;
        o0.x = f2bf(a[0] * inv); o0.y = f2bf(a[1] * inv);
        o0.z = f2bf(a[2] * inv); o0.w = f2bf(a[3] * inv);
        o1.x = f2bf(a[4] * inv); o1.y = f2bf(a[5] * inv);
        o1.z = f2bf(a[6] * inv); o1.w = f2bf(a[7] * inv);
        unsigned short* dst = X + (size_t)i * KX + xoff + f8 * 8;
        *(ushort4*)dst = o0;
        *(ushort4*)(dst + 4) = o1;
    } else {
        float* dst = aggHf + (size_t)i * 64 + f8 * 8;
        *(float4*)dst = make_float4(a[0] * inv, a[1] * inv, a[2] * inv, a[3] * inv);
        *(float4*)(dst + 4) = make_float4(a[4] * inv, a[5] * inv, a[6] * inv, a[7] * inv);
    }
}

// ---------------- per-layer dense update: inst MFMA GEMM blocks + fin blocks ----------------
// GEMM path uses LDS-staged Wt (linear uint4 copy from precomputed wcat_l) —
// round-11 verified configuration (global-B variant measured slower).
__global__ __launch_bounds__(256) void k_dense_layer(
    const unsigned short* __restrict__ X,
    float* __restrict__ inst, unsigned short* __restrict__ inst_bf,
    const int* __restrict__ rpAll,
    const unsigned short* __restrict__ wcat_l,
    const float* __restrict__ bp, const float* __restrict__ bs,
    float* __restrict__ fin,
    const float* __restrict__ aggHf, const float* __restrict__ aggEf,
    const float* __restrict__ Wf, const float* __restrict__ bf) {
    __shared__ __align__(16) unsigned short Wt[64][168];  // [n][k], 336B rows (16-aligned)
    int t = threadIdx.x;

    if (blockIdx.x < NBI) {
        // ---------- instruction-node GEMM path ----------
        {
            const uint4* wsrc = (const uint4*)wcat_l;
            uint4* wdst = (uint4*)&Wt[0][0];
            for (int idx = t; idx < 1344; idx += 256) wdst[idx] = wsrc[idx];
        }
        __syncthreads();

        int wave = t >> 6, lane = t & 63;
        int rowbase = blockIdx.x * 128 + wave * 32;   // this wave's 32 rows
        int lrow = lane & 15, lk = (lane >> 4) * 8;

        f32x4 acc[2][4];
#pragma unroll
        for (int rb = 0; rb < 2; rb++)
#pragma unroll
            for (int nb = 0; nb < 4; nb++) acc[rb][nb] = (f32x4){0.f, 0.f, 0.f, 0.f};

#pragma unroll
        for (int kc = 0; kc < 5; kc++) {
            int k0 = kc * 32 + lk;
            bf16x8 a[2], b[4];
#pragma unroll
            for (int rb = 0; rb < 2; rb++) {
                int r = min(rowbase + rb * 16 + lrow, NI - 1);
                a[rb] = *(const bf16x8*)(X + (size_t)r * KX + k0);
            }
#pragma unroll
            for (int nb = 0; nb < 4; nb++)
                b[nb] = *(const bf16x8*)(&Wt[nb * 16 + lrow][k0]);
#pragma unroll
            for (int rb = 0; rb < 2; rb++)
#pragma unroll
                for (int nb = 0; nb < 4; nb++)
                    acc[rb][nb] = __builtin_amdgcn_mfma_f32_16x16x32_bf16(a[rb], b[nb], acc[rb][nb], 0, 0, 0);
        }

        // epilogue: C[row= (lane>>4)*4+j, col= nb*16 + (lane&15)]
#pragma unroll
        for (int rb = 0; rb < 2; rb++) {
#pragma unroll
            for (int j = 0; j < 4; j++) {
                int node = rowbase + rb * 16 + (lane >> 4) * 4 + j;
                bool v = node < NI;
                int nn = v ? node : NI - 1;
                float mP = (v && (rpAll[nn + 1] > rpAll[nn])) ? 0.5f : 0.f;
                float mS = (v && (rpAll[NI + nn + 1] > rpAll[NI + nn])) ? 0.5f : 0.f;
#pragma unroll
                for (int nb = 0; nb < 4; nb++) {
                    int col = nb * 16 + lrow;
                    float x = inst[(size_t)nn * 64 + col] + acc[rb][nb][j] + mP * bp[col] + mS * bs[col];
                    x = elu1(x);
                    if (v) {
                        inst[(size_t)nn * 64 + col] = x;
                        inst_bf[(size_t)nn * 64 + col] = f2bf(x);
                    }
                }
            }
        }
    } else {
        // ---------- final-node path: thread = (node, j-quad) ----------
        int tid = (blockIdx.x - NBI) * 256 + t;     // 0 .. 31999
        int n = tid >> 4;                           // node 0..1999
        int jq = tid & 15;                          // j-quad 0..15
        const int* rpF = rpAll + 2 * NI;
        int cF = rpF[n + 1] - rpF[n];
        float mF = (cF > 0) ? 1.f : 0.f;
        float invF = 1.f / (float)max(cF, 1);

        float acc0 = bf[jq * 4 + 0], acc1 = bf[jq * 4 + 1];
        float acc2 = bf[jq * 4 + 2], acc3 = bf[jq * 4 + 3];
        const float* hrow = aggHf + (size_t)n * 64;
        for (int k = 0; k < 64; k++) {
            float h = hrow[k];
            float4 w = *(const float4*)(Wf + (size_t)k * 64 + jq * 4);
            acc0 += h * w.x; acc1 += h * w.y; acc2 += h * w.z; acc3 += h * w.w;
        }
        const float* erow = aggEf + (size_t)n * 8;
#pragma unroll
        for (int k = 0; k < 8; k++) {
            float h = erow[k] * invF;
            float4 w = *(const float4*)(Wf + (size_t)(64 + k) * 64 + jq * 4);
            acc0 += h * w.x; acc1 += h * w.y; acc2 += h * w.z; acc3 += h * w.w;
        }
        float4 fv = *(const float4*)(fin + (size_t)n * 64 + jq * 4);
        float4 o;
        o.x = elu1(fv.x + mF * acc0);
        o.y = elu1(fv.y + mF * acc1);
        o.z = elu1(fv.z + mF * acc2);
        o.w = elu1(fv.w + mF * acc3);
        *(float4*)(fin + (size_t)n * 64 + jq * 4) = o;
    }
}

// ---------------- readout head ----------------
__global__ __launch_bounds__(64, 1) void k_head(
    const float* __restrict__ fin,
    const float* __restrict__ Wr1, const float* __restrict__ br1,
    const float* __restrict__ Wr2, const float* __restrict__ br2,
    const float* __restrict__ Wr3, const float* __restrict__ br3,
    float* __restrict__ out) {
    __shared__ float hL[64 * 65];
    const int lane = threadIdx.x;
    const int base = blockIdx.x * 64;

    for (int idx = lane; idx < 1024; idx += 64) {
        int n = idx >> 4, k4 = idx & 15;
        float4 v = ((const float4*)fin)[(size_t)min(base + n, NF - 1) * 16 + k4];
        float* d = &hL[n * 65 + k4 * 4];
        d[0] = v.x; d[1] = v.y; d[2] = v.z; d[3] = v.w;
    }
    __syncthreads();

    float acc[64];
#pragma unroll
    for (int j = 0; j < 64; j++) acc[j] = br1[j];
#pragma unroll 4
    for (int k = 0; k < 64; k++) {
        float h = hL[lane * 65 + k];
#pragma unroll
        for (int j = 0; j < 64; j++) acc[j] += h * Wr1[k * 64 + j];
    }
#pragma unroll
    for (int j = 0; j < 64; j++) hL[lane * 65 + j] = elu1(acc[j]);

#pragma unroll
    for (int j = 0; j < 64; j++) acc[j] = br2[j];
#pragma unroll 4
    for (int k = 0; k < 64; k++) {
        float h = hL[lane * 65 + k];
#pragma unroll
        for (int j = 0; j < 64; j++) acc[j] += h * Wr2[k * 64 + j];
    }
    float r = br3[0];
#pragma unroll
    for (int j = 0; j < 64; j++) r += elu1(acc[j]) * Wr3[j];

    int i = base + lane;
    if (i < NF) out[i] = r;
}

extern "C" void kernel_launch(void* const* d_in, const int* in_sizes, int n_in,
                              void* d_out, int out_size, void* d_ws, size_t ws_size,
                              hipStream_t stream) {
    const float* xi  = (const float*)d_in[0];
    const float* xf  = (const float*)d_in[1];
    const float* xe  = (const float*)d_in[2];
    const float* xef = (const float*)d_in[3];
    const int* prev_src = (const int*)d_in[4];
    const int* prev_dst = (const int*)d_in[5];
    const int* tf_src = (const int*)d_in[6];
    const int* tf_dst = (const int*)d_in[7];
    const float* W_it = (const float*)d_in[8];  const float* b_it = (const float*)d_in[9];
    const float* W_ft = (const float*)d_in[10]; const float* b_ft = (const float*)d_in[11];
    const float* W_ep = (const float*)d_in[12]; const float* b_ep = (const float*)d_in[13];
    const float* W_es = (const float*)d_in[14]; const float* b_es = (const float*)d_in[15];
    const float* W_ef = (const float*)d_in[16]; const float* b_ef = (const float*)d_in[17];
    const float* Wg_prev = (const float*)d_in[18]; const float* bg_prev = (const float*)d_in[19];
    const float* Wg_succ = (const float*)d_in[20]; const float* bg_succ = (const float*)d_in[21];
    const float* Wg_tf   = (const float*)d_in[22]; const float* bg_tf   = (const float*)d_in[23];
    const float* Wr1 = (const float*)d_in[24]; const float* br1 = (const float*)d_in[25];
    const float* Wr2 = (const float*)d_in[26]; const float* br2 = (const float*)d_in[27];
    const float* Wr3 = (const float*)d_in[28]; const float* br3 = (const float*)d_in[29];

    char* ws = (char*)d_ws;
    size_t off = 0;
    auto alloc = [&](size_t bytes) -> char* {
        char* p = ws + off;
        off += (bytes + 255) & ~(size_t)255;
        return p;
    };
    float* inst  = (float*)alloc((size_t)NI * 64 * 4);
    unsigned short* inst_bf = (unsigned short*)alloc((size_t)NI * 64 * 2);
    unsigned short* X = (unsigned short*)alloc((size_t)NI * KX * 2);
    float* fin   = (float*)alloc((size_t)NF * 64 * 4);
    float* aggHf = (float*)alloc((size_t)NF * 64 * 4);
    float* aggEp = (float*)alloc((size_t)NI * 8 * 4);
    float* aggEs = (float*)alloc((size_t)NI * 8 * 4);
    float* aggEf = (float*)alloc((size_t)NF * 8 * 4);
    unsigned short* wcat = (unsigned short*)alloc((size_t)NL * WTN * 2);
    char* zero_begin = ws + off;
    int* cnt  = (int*)alloc((size_t)NT * 4);
    int* fill = (int*)alloc((size_t)NT * 4);
    char* zero_end = ws + off;
    int* rpAll = (int*)alloc((size_t)(NT + 1) * 4);
    int* colP = (int*)alloc((size_t)NE * 4);
    int* colS = (int*)alloc((size_t)NE * 4);
    int* colF = (int*)alloc((size_t)NEF * 4);
    int* bsum = (int*)alloc(1024 * 4);
    (void)ws_size; (void)in_sizes; (void)n_in; (void)out_size;

    // scatter-stage fp32 edge-embed buffers alias regions dead until after k_eagg2:
    //   ePbuf (NE*32B = 25.6MB)  -> X (32MB, live cols written by k_prep_x/spmm later)
    //   eSbuf (NE*32B = 25.6MB)  -> inst (25.6MB, first written by k_node_embed)
    //   eFbuf (NEF*32B = 6.4MB)  -> inst_bf (12.8MB, first written by k_node_embed)
    float* ePbuf = (float*)X;
    float* eSbuf = inst;
    float* eFbuf = (float*)inst_bf;

    hipMemsetAsync(zero_begin, 0, (size_t)(zero_end - zero_begin), stream);

    k_prep_w<<<(NL * WTN + 255) / 256, 256, 0, stream>>>(Wg_prev, Wg_succ, wcat);

    k_count<<<(NE + 255) / 256, 256, 0, stream>>>(prev_src, prev_dst, tf_dst, cnt);

    int nb = (NT + 255) / 256;
    k_scan1<<<nb, 256, 0, stream>>>(cnt, NT, rpAll, bsum);
    k_scan2<<<1, 1024, 0, stream>>>(bsum, nb);
    k_scan3<<<nb, 256, 0, stream>>>(rpAll, bsum, NT);

    k_scatter<<<(NE + 255) / 256, 256, 0, stream>>>(prev_src, prev_dst, tf_src, tf_dst,
                                                    xe, xef, rpAll, fill,
                                                    colP, colS, colF,
                                                    ePbuf, eSbuf, eFbuf,
                                                    W_ep, b_ep, W_es, b_es, W_ef, b_ef);

    k_eagg2<<<(NT + 31) / 32, 256, 0, stream>>>(rpAll, ePbuf, eSbuf, eFbuf,
                                                aggEp, aggEs, aggEf);

    k_prep_x<<<(NI + 255) / 256, 256, 0, stream>>>(rpAll, aggEp, aggEs, X);

    {
        int waves = (NI + NF + 15) / 16;
        int blocks = (waves + 3) / 4;
        k_node_embed<<<blocks, 256, 0, stream>>>(xi, xf, W_it, b_it, W_ft, b_ft,
                                                 inst, inst_bf, fin);
    }

    for (int l = 0; l < NL; l++) {
        // 8 tasks per wave, 32 tasks per 256-thread block; F tasks first
        k_spmm<<<(NT + 31) / 32, 256, 0, stream>>>(inst_bf, rpAll,
                                                   colP, colS, colF,
                                                   X, aggHf);
        k_dense_layer<<<NBI + NBF, 256, 0, stream>>>(X, inst, inst_bf, rpAll,
                                                     wcat + (size_t)l * WTN,
                                                     bg_prev + (size_t)l * 64, bg_succ + (size_t)l * 64,
                                                     fin, aggHf, aggEf,
                                                     Wg_tf + (size_t)l * 72 * 64, bg_tf + (size_t)l * 64);
    }

    k_head<<<(NF + 63) / 64, 64, 0, stream>>>(fin, Wr1, br1, Wr2, br2, Wr3, br3, (float*)d_out);
}